// Round 3
// baseline (63.648 us; speedup 1.0000x reference)
//
#include <hip/hip_runtime.h>

// ItemCode: PQ-coded embedding reconstruction.
//   input_ids : (256, 512) int32
//   item_codes: (1000000, 8) int32
//   centroids : (8, 256, 64) float32   (row 0 of each subspace is all-zero)
//   out       : (256, 512, 512) float32
// out[b,s, m*64+j] = (input_ids[b,s]==0) ? 0 : centroids[m, min(item_codes[id,m],255), j]
//
// Pipelined: per block, 64 tokens in 4 chunks of 16; chunk c+1's random code
// gather (input_ids -> item_codes, the latency-heavy part) is issued into
// registers before chunk c's store stream and committed to the other LDS
// buffer after it. Only chunk 0's gather is latency-exposed.

#define VALS_ 256
#define NTOK_ (256 * 512)
#define TOKS_BLK 64
#define TOK_CHUNK 16
#define CHUNKS (TOKS_BLK / TOK_CHUNK)       // 4
#define THREADS 256
#define ITERS (TOK_CHUNK * 128 / THREADS)   // 8 float4-stores per thread per chunk

typedef float f4 __attribute__((ext_vector_type(4)));

__global__ __launch_bounds__(THREADS) void ItemCode_kernel(
    const int* __restrict__ input_ids,
    const int* __restrict__ item_codes,
    const float* __restrict__ centroids,
    float* __restrict__ out)
{
    __shared__ int s_cidx[2][TOK_CHUNK * 8];    // 2 x 512 B, double-buffered

    const int tid = threadIdx.x;
    const int blk_tok0 = blockIdx.x * TOKS_BLK;

    // staging role: threads 0..127 each fetch one (token, m) code of the chunk
    const int pt = tid >> 3;        // token within chunk
    const int pm = tid & 7;         // PQ sub-space
    const bool stager = (tid < TOK_CHUNK * 8);

    // streaming role: fixed (m, s4) per thread; token advances by 2 per iter
    const int e  = tid & 127;
    const int m  = e >> 4;
    const int s4 = e & 15;
    const int t0 = tid >> 7;        // 0 or 1

    const f4* __restrict__ cent4 = reinterpret_cast<const f4*>(centroids);
    f4* __restrict__ out4 = reinterpret_cast<f4*>(out);

    // gather one chunk's code -> centroid float4-row base (branch-free pads:
    // id==0 routes to code 0, whose centroid row is all-zero by construction)
    auto gather = [&](int c) -> int {
        const int id = input_ids[blk_tok0 + c * TOK_CHUNK + pt];
        int code = __builtin_nontemporal_load(&item_codes[id * 8 + pm]);
        code = min(code, VALS_ - 1);
        code = (id == 0) ? 0 : code;
        return ((pm << 8) + code) << 4;     // float4 index of centroid row base
    };

    int reg;
    if (stager) {
        reg = gather(0);
        s_cidx[0][tid] = reg;
    }

    for (int c = 0; c < CHUNKS; ++c) {
        __syncthreads();                     // s_cidx[c&1] ready
        const bool more = (c + 1 < CHUNKS);
        if (more && stager) reg = gather(c + 1);   // loads in flight under stream

        const int buf = c & 1;
        const int ob = (blk_tok0 + c * TOK_CHUNK) * 128;
        #pragma unroll
        for (int it = 0; it < ITERS; ++it) {
            const int t  = t0 + it * 2;
            const int ci = s_cidx[buf][(t << 3) | m] + s4;
            __builtin_nontemporal_store(cent4[ci], &out4[ob + tid + it * THREADS]);
        }
        if (more && stager) s_cidx[buf ^ 1][tid] = reg;  // waitcnt lands here
    }
}

extern "C" void kernel_launch(void* const* d_in, const int* in_sizes, int n_in,
                              void* d_out, int out_size, void* d_ws, size_t ws_size,
                              hipStream_t stream) {
    const int*   input_ids  = (const int*)d_in[0];
    const int*   item_codes = (const int*)d_in[1];
    const float* centroids  = (const float*)d_in[2];
    float*       out        = (float*)d_out;

    dim3 grid(NTOK_ / TOKS_BLK), block(THREADS);   // 2048 blocks x 256
    ItemCode_kernel<<<grid, block, 0, stream>>>(input_ids, item_codes, centroids, out);
}